// Round 1
// baseline (139.896 us; speedup 1.0000x reference)
//
#include <hip/hip_runtime.h>
#include <hip/hip_bf16.h>

typedef __attribute__((ext_vector_type(8))) __bf16 bf16x8;
typedef __attribute__((ext_vector_type(4))) float f32x4;

#define NROWS 16384
#define DIM   2048
#define NH1   512
#define NH2   32
#define MMEM  2048

// workspace byte offsets (all 32KB-aligned)
#define XO  ((size_t)0)            // x bf16:   16384*2048*2 = 67108864
#define W1O ((size_t)67108864)     // W1 bf16:  512*2048*2   = 2097152
#define W2O ((size_t)69206016)     // W2 bf16:  32*512*2     = 32768
#define AMO ((size_t)69238784)     // a_mem:    2048*32*2    = 131072
#define NMO ((size_t)69369856)     // n_mem:    2048*32*2    = 131072
#define HO  ((size_t)69500928)     // h bf16:   16384*512*2  = 16777216

__device__ __forceinline__ f32x4 mfma16(bf16x8 a, bf16x8 b, f32x4 c) {
    return __builtin_amdgcn_mfma_f32_16x16x32_bf16(a, b, c, 0, 0, 0);
}

__device__ __forceinline__ void gload_lds16(const void* g, void* l) {
    __builtin_amdgcn_global_load_lds(
        (const __attribute__((address_space(1))) void*)g,
        (__attribute__((address_space(3))) void*)l, 16, 0, 0);
}

// ---------------- f32 -> bf16 conversion (vectorized) ----------------
struct bf4 { __bf16 a, b, c, d; };

__global__ void cvt_kernel(const float* __restrict__ in, __bf16* __restrict__ out, int n) {
    const int stride = gridDim.x * blockDim.x;
    for (int i = blockIdx.x * blockDim.x + threadIdx.x; i * 4 < n; i += stride) {
        const int idx = i * 4;
        const float4 v = *reinterpret_cast<const float4*>(in + idx);
        bf4 o = { (__bf16)v.x, (__bf16)v.y, (__bf16)v.z, (__bf16)v.w };
        *reinterpret_cast<bf4*>(out + idx) = o;
    }
}

// ---------------- GEMM1: h = relu(x @ W1^T + b1), bf16 out ----------------
// 128x128 tile, BK=32, 4 waves (2x2), m97-style global_load_lds staging.
__global__ __launch_bounds__(256) void gemm1_kernel(
    const __bf16* __restrict__ X,   // [NROWS][DIM]
    const __bf16* __restrict__ W1,  // [NH1][DIM]
    const float*  __restrict__ b1,  // [NH1]
    __bf16* __restrict__ Hout)      // [NROWS][NH1]
{
    __shared__ __bf16 As[128 * 32];
    __shared__ __bf16 Bs[128 * 32];
    const int tid  = threadIdx.x;
    const int lane = tid & 63;
    const int wave = tid >> 6;
    const int bn = blockIdx.x & 3;   // NH1/128 = 4 col tiles
    const int bm = blockIdx.x >> 2;  // NROWS/128 = 128 row tiles
    const size_t brow = (size_t)bm * 128;
    const int bcol = bn * 128;
    const int wr = wave >> 1, wc = wave & 1;

    f32x4 acc[4][4];
#pragma unroll
    for (int m = 0; m < 4; ++m)
#pragma unroll
        for (int n = 0; n < 4; ++n) acc[m][n] = (f32x4){0.f, 0.f, 0.f, 0.f};

    // staging: thread t loads 16B; chunk c covers rows c*64 + t/4, col bytes (t%4)*16
    const int srow  = tid >> 2;
    const int scolB = (tid & 3) * 16;
    const char* aSrc = (const char*)(X  + (brow + srow) * DIM) + scolB;
    const char* bSrc = (const char*)(W1 + (size_t)(bcol + srow) * DIM) + scolB;
    char* aDst = (char*)As + wave * 1024;
    char* bDst = (char*)Bs + wave * 1024;

    const bf16x8* Asv = (const bf16x8*)As;
    const bf16x8* Bsv = (const bf16x8*)Bs;
    const int l15 = lane & 15;
    const int kc  = lane >> 4;           // k-chunk 0..3
    const int rA = wr * 64 + l15;
    const int rB = wc * 64 + l15;

    for (int k0 = 0; k0 < DIM; k0 += 32) {
        gload_lds16(aSrc, aDst);
        gload_lds16(aSrc + (size_t)64 * DIM * 2, aDst + 4096);
        gload_lds16(bSrc, bDst);
        gload_lds16(bSrc + (size_t)64 * DIM * 2, bDst + 4096);
        aSrc += 64; bSrc += 64;   // advance 32 bf16 in k
        __syncthreads();

        bf16x8 av[4], bv[4];
#pragma unroll
        for (int m = 0; m < 4; ++m) av[m] = Asv[(rA + m * 16) * 4 + kc];
#pragma unroll
        for (int n = 0; n < 4; ++n) bv[n] = Bsv[(rB + n * 16) * 4 + kc];
#pragma unroll
        for (int m = 0; m < 4; ++m)
#pragma unroll
            for (int n = 0; n < 4; ++n)
                acc[m][n] = mfma16(av[m], bv[n], acc[m][n]);
        __syncthreads();
    }

    // epilogue: bias + relu + bf16 store. D layout: col=lane&15, row=(lane>>4)*4+reg
#pragma unroll
    for (int n = 0; n < 4; ++n) {
        const int gcol = bcol + wc * 64 + n * 16 + l15;
        const float bias = b1[gcol];
#pragma unroll
        for (int m = 0; m < 4; ++m) {
            const size_t grow0 = brow + wr * 64 + m * 16 + kc * 4;
#pragma unroll
            for (int r = 0; r < 4; ++r) {
                float v = acc[m][n][r] + bias;
                v = v > 0.f ? v : 0.f;
                Hout[(grow0 + r) * NH1 + gcol] = (__bf16)v;
            }
        }
    }
}

// ---------------- Tail: feat = h@W2^T + b2; scores; sigmoid ----------------
// 64 rows per block, 4 waves, each wave owns 16 rows.
__global__ __launch_bounds__(256) void tail_kernel(
    const __bf16* __restrict__ Hin,  // [NROWS][NH1]
    const __bf16* __restrict__ W2b,  // [NH2][NH1]
    const float*  __restrict__ b2,   // [NH2]
    const __bf16* __restrict__ Am,   // [MMEM][NH2]
    const __bf16* __restrict__ Nm,   // [MMEM][NH2]
    float* __restrict__ out)         // [NROWS]
{
    __shared__ __bf16 featLds[64 * 32];
    const int tid  = threadIdx.x;
    const int lane = tid & 63;
    const int wave = tid >> 6;
    const int rowBase = blockIdx.x * 64;
    const int l15 = lane & 15;
    const int kc  = lane >> 4;

    // GEMM2: feat[16][32] per wave, K=512 in 16 steps
    f32x4 acc0 = {0.f,0.f,0.f,0.f}, acc1 = {0.f,0.f,0.f,0.f};
    const size_t hrow = (size_t)(rowBase + wave * 16 + l15) * NH1;
#pragma unroll
    for (int kk = 0; kk < 16; ++kk) {
        bf16x8 a  = *(const bf16x8*)(Hin + hrow + kk * 32 + kc * 8);
        bf16x8 w0 = *(const bf16x8*)(W2b + (size_t)l15 * NH1 + kk * 32 + kc * 8);
        bf16x8 w1 = *(const bf16x8*)(W2b + (size_t)(16 + l15) * NH1 + kk * 32 + kc * 8);
        acc0 = mfma16(a, w0, acc0);
        acc1 = mfma16(a, w1, acc1);
    }

    // feat -> LDS (bias added), layout [64][32] bf16
    const float bias0 = b2[l15], bias1 = b2[16 + l15];
#pragma unroll
    for (int r = 0; r < 4; ++r) {
        const int lr = wave * 16 + kc * 4 + r;
        featLds[lr * 32 + l15]      = (__bf16)(acc0[r] + bias0);
        featLds[lr * 32 + 16 + l15] = (__bf16)(acc1[r] + bias1);
    }
    __syncthreads();

    // A-frag: feat rows of this wave
    const bf16x8 af = *(const bf16x8*)&featLds[(wave * 16 + l15) * 32 + kc * 8];

    float rmaxA[4], rmaxN[4];
#pragma unroll
    for (int r = 0; r < 4; ++r) { rmaxA[r] = -1e30f; rmaxN[r] = -1e30f; }
    const f32x4 zero = {0.f,0.f,0.f,0.f};
#pragma unroll 2
    for (int jt = 0; jt < MMEM / 16; ++jt) {
        bf16x8 ba = *(const bf16x8*)(Am + (size_t)(jt * 16 + l15) * NH2 + kc * 8);
        bf16x8 bn = *(const bf16x8*)(Nm + (size_t)(jt * 16 + l15) * NH2 + kc * 8);
        f32x4 sa = mfma16(af, ba, zero);
        f32x4 sn = mfma16(af, bn, zero);
#pragma unroll
        for (int r = 0; r < 4; ++r) {
            rmaxA[r] = fmaxf(rmaxA[r], sa[r]);
            rmaxN[r] = fmaxf(rmaxN[r], sn[r]);
        }
    }
    // reduce max across the 16 lanes holding different j-columns of same row
#pragma unroll
    for (int off = 1; off < 16; off <<= 1) {
#pragma unroll
        for (int r = 0; r < 4; ++r) {
            rmaxA[r] = fmaxf(rmaxA[r], __shfl_xor(rmaxA[r], off, 64));
            rmaxN[r] = fmaxf(rmaxN[r], __shfl_xor(rmaxN[r], off, 64));
        }
    }
    if (l15 == 0) {
#pragma unroll
        for (int r = 0; r < 4; ++r) {
            const float d = (rmaxA[r] - rmaxN[r]) * (1.0f / 32.0f);
            out[rowBase + wave * 16 + kc * 4 + r] = 1.0f / (1.0f + __expf(-d));
        }
    }
}

extern "C" void kernel_launch(void* const* d_in, const int* in_sizes, int n_in,
                              void* d_out, int out_size, void* d_ws, size_t ws_size,
                              hipStream_t stream) {
    (void)in_sizes; (void)n_in; (void)out_size; (void)ws_size;
    const float* x  = (const float*)d_in[0];
    const float* W1 = (const float*)d_in[1];
    const float* b1 = (const float*)d_in[2];
    const float* W2 = (const float*)d_in[3];
    const float* b2 = (const float*)d_in[4];
    const float* am = (const float*)d_in[5];
    const float* nm = (const float*)d_in[6];
    float* out = (float*)d_out;
    char* ws = (char*)d_ws;
    __bf16* xb  = (__bf16*)(ws + XO);
    __bf16* w1b = (__bf16*)(ws + W1O);
    __bf16* w2b = (__bf16*)(ws + W2O);
    __bf16* amb = (__bf16*)(ws + AMO);
    __bf16* nmb = (__bf16*)(ws + NMO);
    __bf16* hb  = (__bf16*)(ws + HO);

    cvt_kernel<<<dim3(2048), dim3(256), 0, stream>>>(x,  xb,  NROWS * DIM);
    cvt_kernel<<<dim3(256),  dim3(256), 0, stream>>>(W1, w1b, NH1 * DIM);
    cvt_kernel<<<dim3(16),   dim3(256), 0, stream>>>(W2, w2b, NH2 * NH1);
    cvt_kernel<<<dim3(64),   dim3(256), 0, stream>>>(am, amb, MMEM * NH2);
    cvt_kernel<<<dim3(64),   dim3(256), 0, stream>>>(nm, nmb, MMEM * NH2);

    gemm1_kernel<<<dim3((NROWS / 128) * (NH1 / 128)), dim3(256), 0, stream>>>(xb, w1b, b1, hb);
    tail_kernel<<<dim3(NROWS / 64), dim3(256), 0, stream>>>(hb, w2b, b2, amb, nmb, out);
}

// Round 2
// 110.842 us; speedup vs baseline: 1.2621x; 1.2621x over previous
//
#include <hip/hip_runtime.h>
#include <hip/hip_bf16.h>

typedef __attribute__((ext_vector_type(8))) __bf16 bf16x8;
typedef __attribute__((ext_vector_type(4))) float f32x4;

#define NROWS 16384
#define DIM   2048
#define NH1   512
#define NH2   32
#define MMEM  2048

// workspace byte offsets
#define W1O ((size_t)0)            // W1 bf16:  512*2048*2   = 2097152
#define W2O ((size_t)2097152)      // W2 bf16:  32*512*2     = 32768
#define AMO ((size_t)2129920)      // a_mem:    2048*32*2    = 131072
#define NMO ((size_t)2260992)      // n_mem:    2048*32*2    = 131072
#define HO  ((size_t)2392064)      // h bf16:   16384*512*2  = 16777216

__device__ __forceinline__ f32x4 mfma16(bf16x8 a, bf16x8 b, f32x4 c) {
    return __builtin_amdgcn_mfma_f32_16x16x32_bf16(a, b, c, 0, 0, 0);
}

__device__ __forceinline__ void gload_lds16(const void* g, void* l) {
    __builtin_amdgcn_global_load_lds(
        (const __attribute__((address_space(1))) void*)g,
        (__attribute__((address_space(3))) void*)l, 16, 0, 0);
}

__device__ __forceinline__ bf16x8 cvt8(float4 a, float4 b) {
    bf16x8 o;
    o[0] = (__bf16)a.x; o[1] = (__bf16)a.y; o[2] = (__bf16)a.z; o[3] = (__bf16)a.w;
    o[4] = (__bf16)b.x; o[5] = (__bf16)b.y; o[6] = (__bf16)b.z; o[7] = (__bf16)b.w;
    return o;
}

// ---------------- merged f32 -> bf16 conversion for W1, W2, am, nm ----------------
struct bf4 { __bf16 a, b, c, d; };

__global__ void cvt_all_kernel(const float* __restrict__ w1f, __bf16* __restrict__ w1b,
                               const float* __restrict__ w2f, __bf16* __restrict__ w2b,
                               const float* __restrict__ amf, __bf16* __restrict__ amb,
                               const float* __restrict__ nmf, __bf16* __restrict__ nmb) {
    const int g = blockIdx.x * blockDim.x + threadIdx.x;
    const int T = gridDim.x * blockDim.x;
    for (int i = g; i < (NH1 * DIM) / 4; i += T) {
        const float4 v = *reinterpret_cast<const float4*>(w1f + i * 4);
        *reinterpret_cast<bf4*>(w1b + i * 4) = { (__bf16)v.x, (__bf16)v.y, (__bf16)v.z, (__bf16)v.w };
    }
    for (int i = g; i < (NH2 * NH1) / 4; i += T) {
        const float4 v = *reinterpret_cast<const float4*>(w2f + i * 4);
        *reinterpret_cast<bf4*>(w2b + i * 4) = { (__bf16)v.x, (__bf16)v.y, (__bf16)v.z, (__bf16)v.w };
    }
    for (int i = g; i < (MMEM * NH2) / 4; i += T) {
        const float4 v = *reinterpret_cast<const float4*>(amf + i * 4);
        *reinterpret_cast<bf4*>(amb + i * 4) = { (__bf16)v.x, (__bf16)v.y, (__bf16)v.z, (__bf16)v.w };
    }
    for (int i = g; i < (MMEM * NH2) / 4; i += T) {
        const float4 v = *reinterpret_cast<const float4*>(nmf + i * 4);
        *reinterpret_cast<bf4*>(nmb + i * 4) = { (__bf16)v.x, (__bf16)v.y, (__bf16)v.z, (__bf16)v.w };
    }
}

// ---------------- GEMM1: h = relu(x @ W1^T + b1), x read as f32, cvt fused ----------------
// 128x128 tile, BK=32, 4 waves (2x2). A: reg-staged f32 -> cvt -> ds_write_b128.
// B: global_load_lds width-16 (W1 pre-converted bf16).
__global__ __launch_bounds__(256) void gemm1_kernel(
    const float*  __restrict__ Xf,  // [NROWS][DIM] f32
    const __bf16* __restrict__ W1,  // [NH1][DIM] bf16
    const float*  __restrict__ b1,  // [NH1]
    __bf16* __restrict__ Hout)      // [NROWS][NH1]
{
    __shared__ __bf16 As[128 * 32];
    __shared__ __bf16 Bs[128 * 32];
    const int tid  = threadIdx.x;
    const int lane = tid & 63;
    const int wave = tid >> 6;
    // XCD swizzle: nwg=512, 8 XCDs. XCD c gets orig c*64..c*64+63 (16 row-panels x 4 col-tiles)
    const int b = blockIdx.x;
    const int orig = (b & 7) * 64 + (b >> 3);
    const int bn = orig & 3;   // NH1/128 = 4 col tiles
    const int bm = orig >> 2;  // NROWS/128 = 128 row tiles
    const size_t brow = (size_t)bm * 128;
    const int bcol = bn * 128;
    const int wr = wave >> 1, wc = wave & 1;

    f32x4 acc[4][4];
#pragma unroll
    for (int m = 0; m < 4; ++m)
#pragma unroll
        for (int n = 0; n < 4; ++n) acc[m][n] = (f32x4){0.f, 0.f, 0.f, 0.f};

    // A staging: thread t covers rows {t>>2, (t>>2)+64}, k elems [(t&3)*8, +8) each K-step
    const int sArow = tid >> 2;
    const int sAcol = (tid & 3) * 8;
    const float* aSrc = Xf + (brow + sArow) * (size_t)DIM + sAcol;
    __bf16* aDst0 = As + sArow * 32 + sAcol;
    __bf16* aDst1 = As + (sArow + 64) * 32 + sAcol;

    // B staging: gload_lds, wave-uniform base + lane*16 (linear)
    const int sBrow  = tid >> 2;
    const int sBcolB = (tid & 3) * 16;
    const char* bSrc = (const char*)(W1 + (size_t)(bcol + sBrow) * DIM) + sBcolB;
    char* bDst = (char*)Bs + wave * 1024;

    const bf16x8* Asv = (const bf16x8*)As;
    const bf16x8* Bsv = (const bf16x8*)Bs;
    const int l15 = lane & 15;
    const int kc  = lane >> 4;
    const int rA = wr * 64 + l15;
    const int rB = wc * 64 + l15;

    // prologue: f32 A loads for step 0
    float4 pa0 = *(const float4*)(aSrc);
    float4 pa1 = *(const float4*)(aSrc + 4);
    float4 pa2 = *(const float4*)(aSrc + (size_t)64 * DIM);
    float4 pa3 = *(const float4*)(aSrc + (size_t)64 * DIM + 4);

    for (int k0 = 0; k0 < DIM; k0 += 32) {
        gload_lds16(bSrc, bDst);
        gload_lds16(bSrc + (size_t)64 * DIM * 2, bDst + 4096);
        bSrc += 64;
        *(bf16x8*)aDst0 = cvt8(pa0, pa1);
        *(bf16x8*)aDst1 = cvt8(pa2, pa3);
        __syncthreads();

        // prefetch next K-step's f32 (hidden under MFMA)
        if (k0 + 32 < DIM) {
            const float* s = aSrc + k0 + 32;
            pa0 = *(const float4*)(s);
            pa1 = *(const float4*)(s + 4);
            pa2 = *(const float4*)(s + (size_t)64 * DIM);
            pa3 = *(const float4*)(s + (size_t)64 * DIM + 4);
        }

        bf16x8 av[4], bv[4];
#pragma unroll
        for (int m = 0; m < 4; ++m) av[m] = Asv[(rA + m * 16) * 4 + kc];
#pragma unroll
        for (int n = 0; n < 4; ++n) bv[n] = Bsv[(rB + n * 16) * 4 + kc];
#pragma unroll
        for (int m = 0; m < 4; ++m)
#pragma unroll
            for (int n = 0; n < 4; ++n)
                acc[m][n] = mfma16(av[m], bv[n], acc[m][n]);
        __syncthreads();
    }

    // epilogue: bias + relu + bf16 store. D layout: col=lane&15, row=(lane>>4)*4+reg
#pragma unroll
    for (int n = 0; n < 4; ++n) {
        const int gcol = bcol + wc * 64 + n * 16 + l15;
        const float bias = b1[gcol];
#pragma unroll
        for (int m = 0; m < 4; ++m) {
            const size_t grow0 = brow + wr * 64 + m * 16 + kc * 4;
#pragma unroll
            for (int r = 0; r < 4; ++r) {
                float v = acc[m][n][r] + bias;
                v = v > 0.f ? v : 0.f;
                Hout[(grow0 + r) * NH1 + gcol] = (__bf16)v;
            }
        }
    }
}

// ---------------- Tail: feat = h@W2^T + b2; scores; sigmoid ----------------
__global__ __launch_bounds__(256) void tail_kernel(
    const __bf16* __restrict__ Hin,  // [NROWS][NH1]
    const __bf16* __restrict__ W2b,  // [NH2][NH1]
    const float*  __restrict__ b2,   // [NH2]
    const __bf16* __restrict__ Am,   // [MMEM][NH2]
    const __bf16* __restrict__ Nm,   // [MMEM][NH2]
    float* __restrict__ out)         // [NROWS]
{
    __shared__ __bf16 featLds[64 * 32];
    const int tid  = threadIdx.x;
    const int lane = tid & 63;
    const int wave = tid >> 6;
    const int rowBase = blockIdx.x * 64;
    const int l15 = lane & 15;
    const int kc  = lane >> 4;

    // GEMM2: feat[16][32] per wave, K=512 in 16 steps
    f32x4 acc0 = {0.f,0.f,0.f,0.f}, acc1 = {0.f,0.f,0.f,0.f};
    const size_t hrow = (size_t)(rowBase + wave * 16 + l15) * NH1;
#pragma unroll
    for (int kk = 0; kk < 16; ++kk) {
        bf16x8 a  = *(const bf16x8*)(Hin + hrow + kk * 32 + kc * 8);
        bf16x8 w0 = *(const bf16x8*)(W2b + (size_t)l15 * NH1 + kk * 32 + kc * 8);
        bf16x8 w1 = *(const bf16x8*)(W2b + (size_t)(16 + l15) * NH1 + kk * 32 + kc * 8);
        acc0 = mfma16(a, w0, acc0);
        acc1 = mfma16(a, w1, acc1);
    }

    const float bias0 = b2[l15], bias1 = b2[16 + l15];
#pragma unroll
    for (int r = 0; r < 4; ++r) {
        const int lr = wave * 16 + kc * 4 + r;
        featLds[lr * 32 + l15]      = (__bf16)(acc0[r] + bias0);
        featLds[lr * 32 + 16 + l15] = (__bf16)(acc1[r] + bias1);
    }
    __syncthreads();

    const bf16x8 af = *(const bf16x8*)&featLds[(wave * 16 + l15) * 32 + kc * 8];

    float rmaxA[4], rmaxN[4];
#pragma unroll
    for (int r = 0; r < 4; ++r) { rmaxA[r] = -1e30f; rmaxN[r] = -1e30f; }
    const f32x4 zero = {0.f,0.f,0.f,0.f};
#pragma unroll 2
    for (int jt = 0; jt < MMEM / 16; ++jt) {
        bf16x8 ba = *(const bf16x8*)(Am + (size_t)(jt * 16 + l15) * NH2 + kc * 8);
        bf16x8 bn = *(const bf16x8*)(Nm + (size_t)(jt * 16 + l15) * NH2 + kc * 8);
        f32x4 sa = mfma16(af, ba, zero);
        f32x4 sn = mfma16(af, bn, zero);
#pragma unroll
        for (int r = 0; r < 4; ++r) {
            rmaxA[r] = fmaxf(rmaxA[r], sa[r]);
            rmaxN[r] = fmaxf(rmaxN[r], sn[r]);
        }
    }
#pragma unroll
    for (int off = 1; off < 16; off <<= 1) {
#pragma unroll
        for (int r = 0; r < 4; ++r) {
            rmaxA[r] = fmaxf(rmaxA[r], __shfl_xor(rmaxA[r], off, 64));
            rmaxN[r] = fmaxf(rmaxN[r], __shfl_xor(rmaxN[r], off, 64));
        }
    }
    if (l15 == 0) {
#pragma unroll
        for (int r = 0; r < 4; ++r) {
            const float d = (rmaxA[r] - rmaxN[r]) * (1.0f / 32.0f);
            out[rowBase + wave * 16 + kc * 4 + r] = 1.0f / (1.0f + __expf(-d));
        }
    }
}

extern "C" void kernel_launch(void* const* d_in, const int* in_sizes, int n_in,
                              void* d_out, int out_size, void* d_ws, size_t ws_size,
                              hipStream_t stream) {
    (void)in_sizes; (void)n_in; (void)out_size; (void)ws_size;
    const float* x  = (const float*)d_in[0];
    const float* W1 = (const float*)d_in[1];
    const float* b1 = (const float*)d_in[2];
    const float* W2 = (const float*)d_in[3];
    const float* b2 = (const float*)d_in[4];
    const float* am = (const float*)d_in[5];
    const float* nm = (const float*)d_in[6];
    float* out = (float*)d_out;
    char* ws = (char*)d_ws;
    __bf16* w1b = (__bf16*)(ws + W1O);
    __bf16* w2b = (__bf16*)(ws + W2O);
    __bf16* amb = (__bf16*)(ws + AMO);
    __bf16* nmb = (__bf16*)(ws + NMO);
    __bf16* hb  = (__bf16*)(ws + HO);

    cvt_all_kernel<<<dim3(512), dim3(256), 0, stream>>>(W1, w1b, W2, w2b, am, amb, nm, nmb);
    gemm1_kernel<<<dim3((NROWS / 128) * (NH1 / 128)), dim3(256), 0, stream>>>(x, w1b, b1, hb);
    tail_kernel<<<dim3(NROWS / 64), dim3(256), 0, stream>>>(hb, w2b, b2, amb, nmb, out);
}

// Round 3
// 92.511 us; speedup vs baseline: 1.5122x; 1.1982x over previous
//
#include <hip/hip_runtime.h>
#include <hip/hip_bf16.h>

typedef __attribute__((ext_vector_type(8))) __bf16 bf16x8;
typedef __attribute__((ext_vector_type(4))) float f32x4;

#define NROWS 16384
#define DIM   2048
#define NH1   512
#define NH2   32
#define MMEM  2048
#define NT    (DIM / 32)   // 64 K-steps

// workspace byte offsets
#define W1O ((size_t)0)            // W1 bf16:  512*2048*2   = 2097152
#define W2O ((size_t)2097152)      // W2 bf16:  32*512*2     = 32768
#define AMO ((size_t)2129920)      // a_mem:    2048*32*2    = 131072
#define NMO ((size_t)2260992)      // n_mem:    2048*32*2    = 131072
#define HO  ((size_t)2392064)      // h bf16:   16384*512*2  = 16777216

__device__ __forceinline__ f32x4 mfma16(bf16x8 a, bf16x8 b, f32x4 c) {
    return __builtin_amdgcn_mfma_f32_16x16x32_bf16(a, b, c, 0, 0, 0);
}

__device__ __forceinline__ void gload_lds16(const void* g, void* l) {
    __builtin_amdgcn_global_load_lds(
        (const __attribute__((address_space(1))) void*)g,
        (__attribute__((address_space(3))) void*)l, 16, 0, 0);
}

__device__ __forceinline__ bf16x8 cvt8(float4 a, float4 b) {
    bf16x8 o;
    o[0] = (__bf16)a.x; o[1] = (__bf16)a.y; o[2] = (__bf16)a.z; o[3] = (__bf16)a.w;
    o[4] = (__bf16)b.x; o[5] = (__bf16)b.y; o[6] = (__bf16)b.z; o[7] = (__bf16)b.w;
    return o;
}

// ---------------- merged f32 -> bf16 conversion for W1, W2, am, nm ----------------
struct bf4 { __bf16 a, b, c, d; };

__global__ void cvt_all_kernel(const float* __restrict__ w1f, __bf16* __restrict__ w1b,
                               const float* __restrict__ w2f, __bf16* __restrict__ w2b,
                               const float* __restrict__ amf, __bf16* __restrict__ amb,
                               const float* __restrict__ nmf, __bf16* __restrict__ nmb) {
    const int g = blockIdx.x * blockDim.x + threadIdx.x;
    const int T = gridDim.x * blockDim.x;
    for (int i = g; i < (NH1 * DIM) / 4; i += T) {
        const float4 v = *reinterpret_cast<const float4*>(w1f + i * 4);
        *reinterpret_cast<bf4*>(w1b + i * 4) = { (__bf16)v.x, (__bf16)v.y, (__bf16)v.z, (__bf16)v.w };
    }
    for (int i = g; i < (NH2 * NH1) / 4; i += T) {
        const float4 v = *reinterpret_cast<const float4*>(w2f + i * 4);
        *reinterpret_cast<bf4*>(w2b + i * 4) = { (__bf16)v.x, (__bf16)v.y, (__bf16)v.z, (__bf16)v.w };
    }
    for (int i = g; i < (MMEM * NH2) / 4; i += T) {
        const float4 v = *reinterpret_cast<const float4*>(amf + i * 4);
        *reinterpret_cast<bf4*>(amb + i * 4) = { (__bf16)v.x, (__bf16)v.y, (__bf16)v.z, (__bf16)v.w };
    }
    for (int i = g; i < (MMEM * NH2) / 4; i += T) {
        const float4 v = *reinterpret_cast<const float4*>(nmf + i * 4);
        *reinterpret_cast<bf4*>(nmb + i * 4) = { (__bf16)v.x, (__bf16)v.y, (__bf16)v.z, (__bf16)v.w };
    }
}

// ---------------- GEMM1: h = relu(x @ W1^T + b1), x read as f32, cvt fused ----------------
// 64x128 tile, BK=32, 4 waves (2Mx2N, wave-tile 32x64). Double-buffered LDS,
// one raw s_barrier per K-step, counted vmcnt (never 0 in main loop).
__global__ __launch_bounds__(256) void gemm1_kernel(
    const float*  __restrict__ Xf,  // [NROWS][DIM] f32
    const __bf16* __restrict__ W1,  // [NH1][DIM] bf16
    const float*  __restrict__ b1,  // [NH1]
    __bf16* __restrict__ Hout)      // [NROWS][NH1]
{
    __shared__ __bf16 bufA[2][64 * 32];
    __shared__ __bf16 bufB[2][128 * 32];
    const int tid  = threadIdx.x;
    const int lane = tid & 63;
    const int wave = tid >> 6;
    // XCD swizzle: nwg=1024 (8*128). XCD c gets 128 consecutive orig (32 row-panels x 4 cols)
    const int b = blockIdx.x;
    const int orig = (b & 7) * 128 + (b >> 3);
    const int bn = orig & 3;    // 4 col tiles of 128
    const int bm = orig >> 2;   // 256 row tiles of 64
    const size_t brow = (size_t)bm * 64;
    const int bcol = bn * 128;
    const int wr = wave >> 1, wc = wave & 1;

    f32x4 acc[2][4];
#pragma unroll
    for (int m = 0; m < 2; ++m)
#pragma unroll
        for (int n = 0; n < 4; ++n) acc[m][n] = (f32x4){0.f, 0.f, 0.f, 0.f};

    // A staging: thread t covers row t>>2, k-elems [(t&3)*8, +8) of each 64x32 tile
    const int sArow = tid >> 2;
    const int sAcol = (tid & 3) * 8;
    const float* aSrc = Xf + (brow + sArow) * (size_t)DIM + sAcol;
    const int aOff = sArow * 32 + sAcol;  // bf16 elements within a bufA buffer

    // B staging: gload_lds, wave-uniform base + lane*16 (linear). Thread covers
    // rows {t>>2, (t>>2)+64}, k-bytes [(t&3)*16, +16).
    const char* bSrcBase = (const char*)(W1 + (size_t)(bcol + (tid >> 2)) * DIM) + (tid & 3) * 16;
    const int bDstOff = wave * 1024;      // bytes within a bufB buffer

    const int l15 = lane & 15;
    const int kc  = lane >> 4;
    const int rA = wr * 32 + l15;
    const int rB = wc * 64 + l15;

    // ---- prologue: tile 0 into buffers 0; prefetch A(1) into pa ----
    {
        float4 ta0 = *(const float4*)(aSrc);
        float4 ta1 = *(const float4*)(aSrc + 4);
        *(bf16x8*)(bufA[0] + aOff) = cvt8(ta0, ta1);
        gload_lds16(bSrcBase, (char*)bufB[0] + bDstOff);
        gload_lds16(bSrcBase + (size_t)64 * DIM * 2, (char*)bufB[0] + bDstOff + 4096);
    }
    __builtin_amdgcn_sched_barrier(0);
    float4 pa0 = *(const float4*)(aSrc + 32);
    float4 pa1 = *(const float4*)(aSrc + 36);
    asm volatile("s_waitcnt vmcnt(2) lgkmcnt(0)" ::: "memory");
    __builtin_amdgcn_s_barrier();

    // ---- main loop: compute tile t, stage tile t+1, prefetch A(t+2) ----
    for (int t = 0; t < NT - 1; ++t) {
        const int cur = t & 1;
        const __bf16* Acur = bufA[cur];
        const __bf16* Bcur = bufB[cur];

        // stage B(t+1) into buffer cur^1 (issued first; drained by vmcnt(2) below)
        const char* bS = bSrcBase + (size_t)(t + 1) * 64;
        gload_lds16(bS, (char*)bufB[cur ^ 1] + bDstOff);
        gload_lds16(bS + (size_t)64 * DIM * 2, (char*)bufB[cur ^ 1] + bDstOff + 4096);
        __builtin_amdgcn_sched_barrier(0);

        // prefetch A(t+2) f32 (left in flight across the barrier; clamped when OOB)
        const int tq = (t + 2 < NT) ? (t + 2) : 0;
        const float* qs = aSrc + (size_t)tq * 32;
        float4 qa0 = *(const float4*)(qs);
        float4 qa1 = *(const float4*)(qs + 4);

        // write A(t+1) from pa (loaded a full iteration ago)
        *(bf16x8*)(bufA[cur ^ 1] + aOff) = cvt8(pa0, pa1);

        // compute tile t
        bf16x8 av[2], bv[4];
#pragma unroll
        for (int m = 0; m < 2; ++m) av[m] = *(const bf16x8*)(Acur + (rA + m * 16) * 32 + kc * 8);
#pragma unroll
        for (int n = 0; n < 4; ++n) bv[n] = *(const bf16x8*)(Bcur + (rB + n * 16) * 32 + kc * 8);
#pragma unroll
        for (int m = 0; m < 2; ++m)
#pragma unroll
            for (int n = 0; n < 4; ++n)
                acc[m][n] = mfma16(av[m], bv[n], acc[m][n]);

        // B(t+1) gloads done (2 oldest); qa loads stay outstanding. ds ops visible.
        asm volatile("s_waitcnt vmcnt(2) lgkmcnt(0)" ::: "memory");
        __builtin_amdgcn_s_barrier();
        pa0 = qa0; pa1 = qa1;
    }

    // ---- final tile (NT-1), already staged ----
    {
        const int cur = (NT - 1) & 1;
        const __bf16* Acur = bufA[cur];
        const __bf16* Bcur = bufB[cur];
        bf16x8 av[2], bv[4];
#pragma unroll
        for (int m = 0; m < 2; ++m) av[m] = *(const bf16x8*)(Acur + (rA + m * 16) * 32 + kc * 8);
#pragma unroll
        for (int n = 0; n < 4; ++n) bv[n] = *(const bf16x8*)(Bcur + (rB + n * 16) * 32 + kc * 8);
#pragma unroll
        for (int m = 0; m < 2; ++m)
#pragma unroll
            for (int n = 0; n < 4; ++n)
                acc[m][n] = mfma16(av[m], bv[n], acc[m][n]);
    }

    // epilogue: bias + relu + bf16 store. D layout: col=lane&15, row=(lane>>4)*4+reg
#pragma unroll
    for (int n = 0; n < 4; ++n) {
        const int gcol = bcol + wc * 64 + n * 16 + l15;
        const float bias = b1[gcol];
#pragma unroll
        for (int m = 0; m < 2; ++m) {
            const size_t grow0 = brow + wr * 32 + m * 16 + kc * 4;
#pragma unroll
            for (int r = 0; r < 4; ++r) {
                float v = acc[m][n][r] + bias;
                v = v > 0.f ? v : 0.f;
                Hout[(grow0 + r) * NH1 + gcol] = (__bf16)v;
            }
        }
    }
}

// ---------------- Tail: feat = h@W2^T + b2; scores; sigmoid ----------------
// 512 threads, 64 rows per block. Waves 0-3 compute feat; all 8 waves split
// the j=2048 memory loop in half; LDS max-combine.
__global__ __launch_bounds__(512) void tail_kernel(
    const __bf16* __restrict__ Hin,  // [NROWS][NH1]
    const __bf16* __restrict__ W2b,  // [NH2][NH1]
    const float*  __restrict__ b2,   // [NH2]
    const __bf16* __restrict__ Am,   // [MMEM][NH2]
    const __bf16* __restrict__ Nm,   // [MMEM][NH2]
    float* __restrict__ out)         // [NROWS]
{
    __shared__ __bf16 featLds[64 * 32];
    __shared__ float aMaxLds[2][64];
    __shared__ float nMaxLds[2][64];
    const int tid  = threadIdx.x;
    const int lane = tid & 63;
    const int wave = tid >> 6;          // 0..7
    const int rowBase = blockIdx.x * 64;
    const int l15 = lane & 15;
    const int kc  = lane >> 4;
    const int rgrp  = (wave & 3) * 16;  // 16-row group
    const int jHalf = wave >> 2;        // 0 or 1

    // GEMM2 by waves 0-3: feat[16][32] per wave, K=512 in 16 steps
    if (wave < 4) {
        f32x4 acc0 = {0.f,0.f,0.f,0.f}, acc1 = {0.f,0.f,0.f,0.f};
        const size_t hrow = (size_t)(rowBase + rgrp + l15) * NH1;
#pragma unroll
        for (int kk = 0; kk < 16; ++kk) {
            bf16x8 a  = *(const bf16x8*)(Hin + hrow + kk * 32 + kc * 8);
            bf16x8 w0 = *(const bf16x8*)(W2b + (size_t)l15 * NH1 + kk * 32 + kc * 8);
            bf16x8 w1 = *(const bf16x8*)(W2b + (size_t)(16 + l15) * NH1 + kk * 32 + kc * 8);
            acc0 = mfma16(a, w0, acc0);
            acc1 = mfma16(a, w1, acc1);
        }
        const float bias0 = b2[l15], bias1 = b2[16 + l15];
#pragma unroll
        for (int r = 0; r < 4; ++r) {
            const int lr = rgrp + kc * 4 + r;
            featLds[lr * 32 + l15]      = (__bf16)(acc0[r] + bias0);
            featLds[lr * 32 + 16 + l15] = (__bf16)(acc1[r] + bias1);
        }
    }
    __syncthreads();

    const bf16x8 af = *(const bf16x8*)&featLds[(rgrp + l15) * 32 + kc * 8];

    float rmaxA[4], rmaxN[4];
#pragma unroll
    for (int r = 0; r < 4; ++r) { rmaxA[r] = -1e30f; rmaxN[r] = -1e30f; }
    const f32x4 zero = {0.f,0.f,0.f,0.f};
    const int jBase = jHalf * (MMEM / 2);
#pragma unroll 2
    for (int jt = 0; jt < (MMEM / 2) / 16; jt += 4) {
        bf16x8 ba[4], bb[4];
#pragma unroll
        for (int u = 0; u < 4; ++u) {
            const size_t off = (size_t)(jBase + (jt + u) * 16 + l15) * NH2 + kc * 8;
            ba[u] = *(const bf16x8*)(Am + off);
            bb[u] = *(const bf16x8*)(Nm + off);
        }
#pragma unroll
        for (int u = 0; u < 4; ++u) {
            f32x4 sa = mfma16(af, ba[u], zero);
            f32x4 sn = mfma16(af, bb[u], zero);
#pragma unroll
            for (int r = 0; r < 4; ++r) {
                rmaxA[r] = fmaxf(rmaxA[r], sa[r]);
                rmaxN[r] = fmaxf(rmaxN[r], sn[r]);
            }
        }
    }
    // reduce max across the 16 lanes holding different j-columns of same row
#pragma unroll
    for (int off = 1; off < 16; off <<= 1) {
#pragma unroll
        for (int r = 0; r < 4; ++r) {
            rmaxA[r] = fmaxf(rmaxA[r], __shfl_xor(rmaxA[r], off, 64));
            rmaxN[r] = fmaxf(rmaxN[r], __shfl_xor(rmaxN[r], off, 64));
        }
    }
    if (l15 == 0) {
#pragma unroll
        for (int r = 0; r < 4; ++r) {
            const int row = rgrp + kc * 4 + r;
            aMaxLds[jHalf][row] = rmaxA[r];
            nMaxLds[jHalf][row] = rmaxN[r];
        }
    }
    __syncthreads();
    if (tid < 64) {
        const float ma = fmaxf(aMaxLds[0][tid], aMaxLds[1][tid]);
        const float mn = fmaxf(nMaxLds[0][tid], nMaxLds[1][tid]);
        const float d = (ma - mn) * (1.0f / 32.0f);
        out[rowBase + tid] = 1.0f / (1.0f + __expf(-d));
    }
}

extern "C" void kernel_launch(void* const* d_in, const int* in_sizes, int n_in,
                              void* d_out, int out_size, void* d_ws, size_t ws_size,
                              hipStream_t stream) {
    (void)in_sizes; (void)n_in; (void)out_size; (void)ws_size;
    const float* x  = (const float*)d_in[0];
    const float* W1 = (const float*)d_in[1];
    const float* b1 = (const float*)d_in[2];
    const float* W2 = (const float*)d_in[3];
    const float* b2 = (const float*)d_in[4];
    const float* am = (const float*)d_in[5];
    const float* nm = (const float*)d_in[6];
    float* out = (float*)d_out;
    char* ws = (char*)d_ws;
    __bf16* w1b = (__bf16*)(ws + W1O);
    __bf16* w2b = (__bf16*)(ws + W2O);
    __bf16* amb = (__bf16*)(ws + AMO);
    __bf16* nmb = (__bf16*)(ws + NMO);
    __bf16* hb  = (__bf16*)(ws + HO);

    cvt_all_kernel<<<dim3(512), dim3(256), 0, stream>>>(W1, w1b, W2, w2b, am, amb, nm, nmb);
    gemm1_kernel<<<dim3((NROWS / 64) * (NH1 / 128)), dim3(256), 0, stream>>>(x, w1b, b1, hb);
    tail_kernel<<<dim3(NROWS / 64), dim3(512), 0, stream>>>(hb, w2b, b2, amb, nmb, out);
}